// Round 6
// baseline (2144.780 us; speedup 1.0000x reference)
//
#include <hip/hip_runtime.h>
#include <hip/hip_bf16.h>
#include <stdint.h>
#include <math.h>

#define NIN_  512
#define NOUT_ 128
#define CIN_  128
#define COUT_ 32
#define MO_   4096   // NOUT*COUT
#define NQ_   64     // n-chunks for route (8 n each)

typedef __attribute__((ext_vector_type(4))) float f32x4;

// ---------------------------------------------------------------------------
// K1 (fp32): u[n][bl][mo] = sum_c W1[n][mo][c] * x[b0+bl][n][c]
// grid = 512 n * 16 mo-tiles(256); block 256 = 4 waves.
// W staged in LDS as XOR-swizzled float4 units (conflict-free b128).
// (unchanged — near BW-bound)
// ---------------------------------------------------------------------------
__global__ __launch_bounds__(256) void k_build(const float* __restrict__ x,
                                               const float* __restrict__ W1,
                                               float* __restrict__ u,
                                               int NB, int b0) {
    const int n   = blockIdx.x >> 4;
    const int mt  = blockIdx.x & 15;
    const int mo0 = mt * 256;
    const int t   = threadIdx.x;
    const int l   = t & 63;
    const int bg  = t >> 6;

    __shared__ f32x4 xs4[32 * 32];   // [bl][cu]  16 KB
    __shared__ f32x4 ws4[256 * 8];   // swizzled   32 KB

    const int nxu = NB * 32;
    for (int k = t; k < nxu; k += 256) {
        const int bl = k >> 5;
        const int cu = k & 31;
        xs4[k] = *(const f32x4*)(x + (((size_t)(b0 + bl) * NIN_ + n) * CIN_ + cu * 4));
    }

    const int cu8 = t & 7;
    const int row = t >> 3;
    const int active = (bg < (NB >> 3));

    float acc[4][8];
#pragma unroll
    for (int i = 0; i < 4; ++i)
#pragma unroll
        for (int j = 0; j < 8; ++j) acc[i][j] = 0.f;

    f32x4 wr[8];
#pragma unroll
    for (int p = 0; p < 8; ++p) {
        const int ml = row + p * 32;
        wr[p] = *(const f32x4*)(W1 + ((size_t)(n * MO_ + mo0 + ml) * CIN_ + 0 * 32 + cu8 * 4));
    }

    for (int ch = 0; ch < 4; ++ch) {
        __syncthreads();
#pragma unroll
        for (int p = 0; p < 8; ++p) {
            const int ml = row + p * 32;
            ws4[ml * 8 + (cu8 ^ (ml & 7))] = wr[p];
        }
        __syncthreads();
        if (ch < 3) {
#pragma unroll
            for (int p = 0; p < 8; ++p) {
                const int ml = row + p * 32;
                wr[p] = *(const f32x4*)(W1 + ((size_t)(n * MO_ + mo0 + ml) * CIN_ + (ch + 1) * 32 + cu8 * 4));
            }
        }
        if (active) {
#pragma unroll
            for (int c4 = 0; c4 < 8; ++c4) {
                f32x4 wv[4];
#pragma unroll
                for (int i = 0; i < 4; ++i)
                    wv[i] = ws4[(l + i * 64) * 8 + (c4 ^ (l & 7))];
                f32x4 xq[8];
#pragma unroll
                for (int j = 0; j < 8; ++j)
                    xq[j] = xs4[(bg * 8 + j) * 32 + ch * 8 + c4];
#pragma unroll
                for (int i = 0; i < 4; ++i)
#pragma unroll
                    for (int j = 0; j < 8; ++j) {
                        acc[i][j] += wv[i][0] * xq[j][0];
                        acc[i][j] += wv[i][1] * xq[j][1];
                        acc[i][j] += wv[i][2] * xq[j][2];
                        acc[i][j] += wv[i][3] * xq[j][3];
                    }
            }
        }
    }

    if (active) {
#pragma unroll
        for (int i = 0; i < 4; ++i)
#pragma unroll
            for (int j = 0; j < 8; ++j)
                u[((size_t)n * NB + bg * 8 + j) * MO_ + mo0 + i * 64 + l] = acc[i][j];
    }
}

// ---------------------------------------------------------------------------
// Route chunk body — one wave handles (bl, 8 n's), accumulating sacc for its
// m-half H (units H*8..H*8+7). Full bn[16] computed per wave (wave-private
// softmax, shfl only, NO LDS/barriers). blog is ping-pong: read blogR, write
// blogW (wave H==0, lanes l%8==0 only). Softmax sums in fixed unit order so
// both waves get bitwise-identical c.
// Unit mapping (R2/R4): f32x4 unit f = j*64+l; m = j*8 + (l>>3); o-quad = l&7.
// ---------------------------------------------------------------------------
template<int MODE, int H>
static __device__ __forceinline__ void route_chunk(const float* __restrict__ u,
                                                   const float* __restrict__ vws,
                                                   const float* __restrict__ blogR,
                                                   float* __restrict__ blogW,
                                                   float* __restrict__ spart,
                                                   int NB, int bl, int q, int l) {
    const int sub = l >> 3;

    f32x4 sacc[8];
#pragma unroll
    for (int jj = 0; jj < 8; ++jj) sacc[jj] = (f32x4){0.f, 0.f, 0.f, 0.f};

    for (int nn = 0; nn < 8; ++nn) {
        const int n = q * 8 + nn;
        const f32x4* up = (const f32x4*)(u + ((size_t)n * NB + bl) * MO_);

        if (MODE == 0) {
            const float cu = 1.0f / 128.0f;
#pragma unroll
            for (int jj = 0; jj < 8; ++jj) {
                const f32x4 uo = up[(H * 8 + jj) * 64 + l];
                sacc[jj][0] += cu * uo[0]; sacc[jj][1] += cu * uo[1];
                sacc[jj][2] += cu * uo[2]; sacc[jj][3] += cu * uo[3];
            }
        } else {
            const f32x4* vp = (const f32x4*)(vws + (size_t)bl * MO_);
            const float* bpR = blogR + ((size_t)bl * NIN_ + n) * NOUT_;

            float bnO[8];    // other half (units OTH..OTH+7)
            float bnH[8];    // own half   (units OWN..OWN+7)
            f32x4 urh[8];
            constexpr int OWN = H * 8;
            constexpr int OTH = 8 - H * 8;

            // other half first (u regs die immediately)
#pragma unroll
            for (int jj = 0; jj < 8; ++jj) {
                const int j = OTH + jj;
                const f32x4 uo = up[j * 64 + l];
                const f32x4 vo = vp[j * 64 + l];
                float p = uo[0] * vo[0] + uo[1] * vo[1] + uo[2] * vo[2] + uo[3] * vo[3];
                p += __shfl_xor(p, 1, 64);
                p += __shfl_xor(p, 2, 64);
                p += __shfl_xor(p, 4, 64);
                bnO[jj] = ((MODE == 1) ? 0.f : bpR[j * 8 + sub]) + p;
            }
            // own half (keep u regs for the c·u accumulation)
#pragma unroll
            for (int jj = 0; jj < 8; ++jj) {
                const int j = OWN + jj;
                urh[jj] = up[j * 64 + l];
                const f32x4 vo = vp[j * 64 + l];
                float p = urh[jj][0] * vo[0] + urh[jj][1] * vo[1]
                        + urh[jj][2] * vo[2] + urh[jj][3] * vo[3];
                p += __shfl_xor(p, 1, 64);
                p += __shfl_xor(p, 2, 64);
                p += __shfl_xor(p, 4, 64);
                bnH[jj] = ((MODE == 1) ? 0.f : bpR[j * 8 + sub]) + p;
            }

            if (H == 0 && (l & 7) == 0) {
                float* bpW = blogW + ((size_t)bl * NIN_ + n) * NOUT_;
#pragma unroll
                for (int jj = 0; jj < 8; ++jj) bpW[(OWN + jj) * 8 + sub] = bnH[jj];
#pragma unroll
                for (int jj = 0; jj < 8; ++jj) bpW[(OTH + jj) * 8 + sub] = bnO[jj];
            }

            // softmax over 128 m: lane-local max/sum (order fixed: units 0..15)
            float mx = -1e30f;
#pragma unroll
            for (int jj = 0; jj < 8; ++jj) mx = fmaxf(mx, fmaxf(bnO[jj], bnH[jj]));
            mx = fmaxf(mx, __shfl_xor(mx, 8, 64));
            mx = fmaxf(mx, __shfl_xor(mx, 16, 64));
            mx = fmaxf(mx, __shfl_xor(mx, 32, 64));

#pragma unroll
            for (int jj = 0; jj < 8; ++jj) bnO[jj] = expf(bnO[jj] - mx);
#pragma unroll
            for (int jj = 0; jj < 8; ++jj) bnH[jj] = expf(bnH[jj] - mx);
            float seLo = 0.f, seHi = 0.f;   // fixed unit order: 0..7 then 8..15
#pragma unroll
            for (int jj = 0; jj < 8; ++jj) {
                if (H == 0) { seLo += bnH[jj]; } else { seLo += bnO[jj]; }
            }
#pragma unroll
            for (int jj = 0; jj < 8; ++jj) {
                if (H == 0) { seHi += bnO[jj]; } else { seHi += bnH[jj]; }
            }
            float se = seLo + seHi;
            se += __shfl_xor(se, 8, 64);
            se += __shfl_xor(se, 16, 64);
            se += __shfl_xor(se, 32, 64);
            const float inv = 1.0f / se;

#pragma unroll
            for (int jj = 0; jj < 8; ++jj) {
                const float c = bnH[jj] * inv;
                sacc[jj][0] += c * urh[jj][0]; sacc[jj][1] += c * urh[jj][1];
                sacc[jj][2] += c * urh[jj][2]; sacc[jj][3] += c * urh[jj][3];
            }
        }
    }

    f32x4* sp = (f32x4*)(spart + ((size_t)q * NB + bl) * MO_);
#pragma unroll
    for (int jj = 0; jj < 8; ++jj) sp[(H * 8 + jj) * 64 + l] = sacc[jj];
}

// ---------------------------------------------------------------------------
// K2 fused routing iteration (fp32). MODE: 0 = uniform c, 1 = first (blog=0),
// 2 = normal. grid = NB*NQ_; block 128 = 2 waves (m-halves of one (bl,chunk)).
// ---------------------------------------------------------------------------
template<int MODE>
__global__ __launch_bounds__(128, 4) void k_route(const float* __restrict__ u,
                                                  const float* __restrict__ vws,
                                                  const float* __restrict__ blogR,
                                                  float* __restrict__ blogW,
                                                  float* __restrict__ spart,
                                                  int NB) {
    const int bl = blockIdx.x % NB;
    const int q  = blockIdx.x / NB;      // 0..NQ_-1
    const int l  = threadIdx.x & 63;
    if (threadIdx.x < 64) route_chunk<MODE, 0>(u, vws, blogR, blogW, spart, NB, bl, q, l);
    else                  route_chunk<MODE, 1>(u, vws, blogR, blogW, spart, NB, bl, q, l);
}

// ---------------------------------------------------------------------------
// K3: s = sum_q spart; v = |s|*s/(0.5+s^2) -> vws   (vectorized f32x4)
// grid = NB*MO_/4/256 blocks.
// ---------------------------------------------------------------------------
__global__ __launch_bounds__(256) void k_squash_mid(const float* __restrict__ spart,
                                                    float* __restrict__ vws, int NB) {
    const int j4 = blockIdx.x * 256 + threadIdx.x;      // f32x4 unit index
    const size_t stride4 = (size_t)NB * MO_ / 4;
    const f32x4* sp4 = (const f32x4*)spart;
    f32x4 s = {0.f, 0.f, 0.f, 0.f};
#pragma unroll 8
    for (int qq = 0; qq < NQ_; ++qq) {
        const f32x4 v = sp4[(size_t)qq * stride4 + j4];
        s[0] += v[0]; s[1] += v[1]; s[2] += v[2]; s[3] += v[3];
    }
    f32x4 r;
#pragma unroll
    for (int c = 0; c < 4; ++c) {
        const float s2 = s[c] * s[c];
        r[c] = (sqrtf(s2) / (0.5f + s2)) * s[c];
    }
    ((f32x4*)vws)[j4] = r;
}

// ---------------------------------------------------------------------------
// K4: final squash -> poses (fp32, [b][m][o]) + activations [b][m]
// ---------------------------------------------------------------------------
__global__ __launch_bounds__(256) void k_squash_fin(const float* __restrict__ spart,
                                                    float* __restrict__ out,
                                                    int NB, int b0) {
    const int j = blockIdx.x * 256 + threadIdx.x;
    const size_t stride = (size_t)NB * MO_;
    float s = 0.f;
#pragma unroll 8
    for (int q = 0; q < NQ_; ++q) s += spart[q * stride + j];
    const float s2 = s * s;
    const float v = (sqrtf(s2) / (0.5f + s2)) * s;
    out[(size_t)b0 * MO_ + j] = v;

    float v2 = v * v;
#pragma unroll
    for (int d = 16; d >= 1; d >>= 1) v2 += __shfl_xor(v2, d, 64);
    if ((j & 31) == 0) {
        const int bl = j >> 12;
        const int m  = (j >> 5) & 127;
        out[131072 + (size_t)(b0 + bl) * NOUT_ + m] = sqrtf(v2);
    }
}

// ---------------------------------------------------------------------------
extern "C" void kernel_launch(void* const* d_in, const int* in_sizes, int n_in,
                              void* d_out, int out_size, void* d_ws, size_t ws_size,
                              hipStream_t stream) {
    const float* x  = (const float*)d_in[0];
    const float* W1 = (const float*)d_in[1];
    float* out = (float*)d_out;

    const size_t need32 = (size_t)32 * NIN_ * MO_ * 4            // u
                        + (size_t)2 * 32 * NIN_ * NOUT_ * 4      // blog A+B
                        + (size_t)32 * MO_ * 4                   // vws
                        + (size_t)NQ_ * 32 * MO_ * 4;            // spart
    const int NB = (ws_size >= need32) ? 32 : 16;
    const int npass = 32 / NB;

    char* ws = (char*)d_ws;
    const size_t bytes_u  = (size_t)NB * NIN_ * MO_ * 4;
    const size_t bytes_bl = (size_t)NB * NIN_ * NOUT_ * 4;
    const size_t bytes_v  = (size_t)NB * MO_ * 4;
    float* u     = (float*)(ws);
    float* blogA = (float*)(ws + bytes_u);
    float* blogB = (float*)(ws + bytes_u + bytes_bl);
    float* vws   = (float*)(ws + bytes_u + 2 * bytes_bl);
    float* spart = (float*)(ws + bytes_u + 2 * bytes_bl + bytes_v);

    const int rgrid = NB * NQ_;
    const int mgrid = (NB * MO_ / 4) / 256;
    const int fgrid = NB * 16;

    for (int pass = 0; pass < npass; ++pass) {
        const int b0 = pass * NB;

        k_build<<<8192, 256, 0, stream>>>(x, W1, u, NB, b0);

        // iteration 1: uniform c (softmax of zeros)
        k_route<0><<<rgrid, 128, 0, stream>>>(u, vws, blogA, blogB, spart, NB);
        k_squash_mid<<<mgrid, 256, 0, stream>>>(spart, vws, NB);

        for (int it = 1; it <= 9; ++it) {
            // ping-pong: odd it reads A writes B; even it reads B writes A.
            // (it=1 reads nothing — MODE 1 — and writes B.)
            float* br = (it & 1) ? blogA : blogB;
            float* bw = (it & 1) ? blogB : blogA;
            if (it == 1) k_route<1><<<rgrid, 128, 0, stream>>>(u, vws, br, bw, spart, NB);
            else         k_route<2><<<rgrid, 128, 0, stream>>>(u, vws, br, bw, spart, NB);
            if (it < 9) k_squash_mid<<<mgrid, 256, 0, stream>>>(spart, vws, NB);
            else        k_squash_fin<<<fgrid, 256, 0, stream>>>(spart, out, NB, b0);
        }
    }
}

// Round 7
// 1565.567 us; speedup vs baseline: 1.3700x; 1.3700x over previous
//
#include <hip/hip_runtime.h>
#include <hip/hip_bf16.h>
#include <stdint.h>
#include <math.h>

#define NIN_  512
#define NOUT_ 128
#define CIN_  128
#define COUT_ 32
#define MO_   4096   // NOUT*COUT
#define NQ_   64     // n-chunks for route (8 n each)

typedef __attribute__((ext_vector_type(4))) float f32x4;

// ---------------------------------------------------------------------------
// K1 (fp32): u[n][bl][mo] = sum_c W1[n][mo][c] * x[b0+bl][n][c]
// grid = 512 n * 16 mo-tiles(256); block 256 = 4 waves.
// W staged in LDS as XOR-swizzled float4 units (conflict-free b128).
// (unchanged — near BW-bound; proven R2/R4)
// ---------------------------------------------------------------------------
__global__ __launch_bounds__(256) void k_build(const float* __restrict__ x,
                                               const float* __restrict__ W1,
                                               float* __restrict__ u,
                                               int NB, int b0) {
    const int n   = blockIdx.x >> 4;
    const int mt  = blockIdx.x & 15;
    const int mo0 = mt * 256;
    const int t   = threadIdx.x;
    const int l   = t & 63;
    const int bg  = t >> 6;

    __shared__ f32x4 xs4[32 * 32];   // [bl][cu]  16 KB
    __shared__ f32x4 ws4[256 * 8];   // swizzled   32 KB

    const int nxu = NB * 32;
    for (int k = t; k < nxu; k += 256) {
        const int bl = k >> 5;
        const int cu = k & 31;
        xs4[k] = *(const f32x4*)(x + (((size_t)(b0 + bl) * NIN_ + n) * CIN_ + cu * 4));
    }

    const int cu8 = t & 7;
    const int row = t >> 3;
    const int active = (bg < (NB >> 3));

    float acc[4][8];
#pragma unroll
    for (int i = 0; i < 4; ++i)
#pragma unroll
        for (int j = 0; j < 8; ++j) acc[i][j] = 0.f;

    f32x4 wr[8];
#pragma unroll
    for (int p = 0; p < 8; ++p) {
        const int ml = row + p * 32;
        wr[p] = *(const f32x4*)(W1 + ((size_t)(n * MO_ + mo0 + ml) * CIN_ + 0 * 32 + cu8 * 4));
    }

    for (int ch = 0; ch < 4; ++ch) {
        __syncthreads();
#pragma unroll
        for (int p = 0; p < 8; ++p) {
            const int ml = row + p * 32;
            ws4[ml * 8 + (cu8 ^ (ml & 7))] = wr[p];
        }
        __syncthreads();
        if (ch < 3) {
#pragma unroll
            for (int p = 0; p < 8; ++p) {
                const int ml = row + p * 32;
                wr[p] = *(const f32x4*)(W1 + ((size_t)(n * MO_ + mo0 + ml) * CIN_ + (ch + 1) * 32 + cu8 * 4));
            }
        }
        if (active) {
#pragma unroll
            for (int c4 = 0; c4 < 8; ++c4) {
                f32x4 wv[4];
#pragma unroll
                for (int i = 0; i < 4; ++i)
                    wv[i] = ws4[(l + i * 64) * 8 + (c4 ^ (l & 7))];
                f32x4 xq[8];
#pragma unroll
                for (int j = 0; j < 8; ++j)
                    xq[j] = xs4[(bg * 8 + j) * 32 + ch * 8 + c4];
#pragma unroll
                for (int i = 0; i < 4; ++i)
#pragma unroll
                    for (int j = 0; j < 8; ++j) {
                        acc[i][j] += wv[i][0] * xq[j][0];
                        acc[i][j] += wv[i][1] * xq[j][1];
                        acc[i][j] += wv[i][2] * xq[j][2];
                        acc[i][j] += wv[i][3] * xq[j][3];
                    }
            }
        }
    }

    if (active) {
#pragma unroll
        for (int i = 0; i < 4; ++i)
#pragma unroll
            for (int j = 0; j < 8; ++j)
                u[((size_t)n * NB + bg * 8 + j) * MO_ + mo0 + i * 64 + l] = acc[i][j];
    }
}

// ---------------------------------------------------------------------------
// K2 fused routing iteration (fp32) — m-per-lane layout.
// MODE: 0 = uniform c, 1 = first agree (blog=0), 2 = normal
// grid = (NB/4)*NQ_; block 256 = 4 waves; wave -> bl = bg*4+w; block -> q (8 n).
// Lane l owns m-rows {l, 64+l}: 8 contiguous f32x4 each of u/v/sacc.
// o-dot is in-lane (no shfl); softmax = 6+6 butterfly shfl; exp once per m.
// blog layout [bl][n][m]: lane reads/writes +l, +64+l — coalesced.
// All wave-private (no LDS, no barriers) — post-timing-safe like R2/R4.
// ---------------------------------------------------------------------------
template<int MODE>
__global__ __launch_bounds__(256, 2) void k_route(const float* __restrict__ u,
                                                  const float* __restrict__ vws,
                                                  float* __restrict__ blog,
                                                  float* __restrict__ spart,
                                                  int NB) {
    const int nbg = NB >> 2;
    const int bg  = blockIdx.x % nbg;
    const int q   = blockIdx.x / nbg;   // 0..NQ_-1
    const int w   = threadIdx.x >> 6;
    const int l   = threadIdx.x & 63;
    const int bl  = bg * 4 + w;

    f32x4 vr[2][8];
    if (MODE != 0) {
        const f32x4* vp = (const f32x4*)(vws + (size_t)bl * MO_);
#pragma unroll
        for (int r = 0; r < 2; ++r)
#pragma unroll
            for (int i = 0; i < 8; ++i)
                vr[r][i] = vp[(r * 64 + l) * 8 + i];
    }

    f32x4 sacc[2][8];
#pragma unroll
    for (int r = 0; r < 2; ++r)
#pragma unroll
        for (int i = 0; i < 8; ++i) sacc[r][i] = (f32x4){0.f, 0.f, 0.f, 0.f};

    for (int nn = 0; nn < 8; ++nn) {
        const int n = q * 8 + nn;
        const f32x4* up = (const f32x4*)(u + ((size_t)n * NB + bl) * MO_);
        f32x4 ur[2][8];
#pragma unroll
        for (int r = 0; r < 2; ++r)
#pragma unroll
            for (int i = 0; i < 8; ++i)
                ur[r][i] = up[(r * 64 + l) * 8 + i];

        if (MODE == 0) {
            const float cu = 1.0f / 128.0f;
#pragma unroll
            for (int r = 0; r < 2; ++r)
#pragma unroll
                for (int i = 0; i < 8; ++i) {
                    sacc[r][i][0] += cu * ur[r][i][0];
                    sacc[r][i][1] += cu * ur[r][i][1];
                    sacc[r][i][2] += cu * ur[r][i][2];
                    sacc[r][i][3] += cu * ur[r][i][3];
                }
        } else {
            float* bp = blog + ((size_t)bl * NIN_ + n) * NOUT_;
            float bn[2];
#pragma unroll
            for (int r = 0; r < 2; ++r) {
                float p = 0.f;
#pragma unroll
                for (int i = 0; i < 8; ++i) {
                    p += vr[r][i][0] * ur[r][i][0];
                    p += vr[r][i][1] * ur[r][i][1];
                    p += vr[r][i][2] * ur[r][i][2];
                    p += vr[r][i][3] * ur[r][i][3];
                }
                bn[r] = ((MODE == 1) ? 0.f : bp[r * 64 + l]) + p;
            }
            bp[l]      = bn[0];
            bp[64 + l] = bn[1];

            float mx = fmaxf(bn[0], bn[1]);
            mx = fmaxf(mx, __shfl_xor(mx, 1, 64));
            mx = fmaxf(mx, __shfl_xor(mx, 2, 64));
            mx = fmaxf(mx, __shfl_xor(mx, 4, 64));
            mx = fmaxf(mx, __shfl_xor(mx, 8, 64));
            mx = fmaxf(mx, __shfl_xor(mx, 16, 64));
            mx = fmaxf(mx, __shfl_xor(mx, 32, 64));

            const float e0 = expf(bn[0] - mx);
            const float e1 = expf(bn[1] - mx);
            float se = e0 + e1;
            se += __shfl_xor(se, 1, 64);
            se += __shfl_xor(se, 2, 64);
            se += __shfl_xor(se, 4, 64);
            se += __shfl_xor(se, 8, 64);
            se += __shfl_xor(se, 16, 64);
            se += __shfl_xor(se, 32, 64);
            const float inv = 1.0f / se;
            const float c0 = e0 * inv;
            const float c1 = e1 * inv;

#pragma unroll
            for (int i = 0; i < 8; ++i) {
                sacc[0][i][0] += c0 * ur[0][i][0];
                sacc[0][i][1] += c0 * ur[0][i][1];
                sacc[0][i][2] += c0 * ur[0][i][2];
                sacc[0][i][3] += c0 * ur[0][i][3];
                sacc[1][i][0] += c1 * ur[1][i][0];
                sacc[1][i][1] += c1 * ur[1][i][1];
                sacc[1][i][2] += c1 * ur[1][i][2];
                sacc[1][i][3] += c1 * ur[1][i][3];
            }
        }
    }

    f32x4* sp = (f32x4*)(spart + ((size_t)q * NB + bl) * MO_);
#pragma unroll
    for (int r = 0; r < 2; ++r)
#pragma unroll
        for (int i = 0; i < 8; ++i)
            sp[(r * 64 + l) * 8 + i] = sacc[r][i];
}

// ---------------------------------------------------------------------------
// K3: s = sum_q spart; v = |s|*s/(0.5+s^2) -> vws      (mid iterations)
// ---------------------------------------------------------------------------
__global__ __launch_bounds__(256) void k_squash_mid(const float* __restrict__ spart,
                                                    float* __restrict__ vws, int NB) {
    const int j = blockIdx.x * 256 + threadIdx.x;
    const size_t stride = (size_t)NB * MO_;
    float s = 0.f;
#pragma unroll
    for (int q = 0; q < NQ_; ++q) s += spart[q * stride + j];
    const float s2 = s * s;
    vws[j] = (sqrtf(s2) / (0.5f + s2)) * s;
}

// ---------------------------------------------------------------------------
// K4: final squash -> poses (fp32, [b][m][o]) + activations [b][m]
// ---------------------------------------------------------------------------
__global__ __launch_bounds__(256) void k_squash_fin(const float* __restrict__ spart,
                                                    float* __restrict__ out,
                                                    int NB, int b0) {
    const int j = blockIdx.x * 256 + threadIdx.x;
    const size_t stride = (size_t)NB * MO_;
    float s = 0.f;
#pragma unroll
    for (int q = 0; q < NQ_; ++q) s += spart[q * stride + j];
    const float s2 = s * s;
    const float v = (sqrtf(s2) / (0.5f + s2)) * s;
    out[(size_t)b0 * MO_ + j] = v;

    float v2 = v * v;
#pragma unroll
    for (int d = 16; d >= 1; d >>= 1) v2 += __shfl_xor(v2, d, 64);
    if ((j & 31) == 0) {
        const int bl = j >> 12;
        const int m  = (j >> 5) & 127;
        out[131072 + (size_t)(b0 + bl) * NOUT_ + m] = sqrtf(v2);
    }
}

// ---------------------------------------------------------------------------
extern "C" void kernel_launch(void* const* d_in, const int* in_sizes, int n_in,
                              void* d_out, int out_size, void* d_ws, size_t ws_size,
                              hipStream_t stream) {
    const float* x  = (const float*)d_in[0];
    const float* W1 = (const float*)d_in[1];
    float* out = (float*)d_out;

    const size_t need32 = (size_t)32 * NIN_ * MO_ * 4          // u
                        + (size_t)32 * NIN_ * NOUT_ * 4        // blog
                        + (size_t)32 * MO_ * 4                 // vws
                        + (size_t)NQ_ * 32 * MO_ * 4;          // spart
    const int NB = (ws_size >= need32) ? 32 : 16;
    const int npass = 32 / NB;

    char* ws = (char*)d_ws;
    const size_t bytes_u  = (size_t)NB * NIN_ * MO_ * 4;
    const size_t bytes_bl = (size_t)NB * NIN_ * NOUT_ * 4;
    const size_t bytes_v  = (size_t)NB * MO_ * 4;
    float* u     = (float*)(ws);
    float* blog  = (float*)(ws + bytes_u);
    float* vws   = (float*)(ws + bytes_u + bytes_bl);
    float* spart = (float*)(ws + bytes_u + bytes_bl + bytes_v);

    const int rgrid = (NB / 4) * NQ_;

    for (int pass = 0; pass < npass; ++pass) {
        const int b0 = pass * NB;

        k_build<<<8192, 256, 0, stream>>>(x, W1, u, NB, b0);

        // iteration 1: uniform c
        k_route<0><<<rgrid, 256, 0, stream>>>(u, vws, blog, spart, NB);
        k_squash_mid<<<NB * 16, 256, 0, stream>>>(spart, vws, NB);

        for (int it = 1; it <= 9; ++it) {
            if (it == 1) k_route<1><<<rgrid, 256, 0, stream>>>(u, vws, blog, spart, NB);
            else         k_route<2><<<rgrid, 256, 0, stream>>>(u, vws, blog, spart, NB);
            if (it < 9) k_squash_mid<<<NB * 16, 256, 0, stream>>>(spart, vws, NB);
            else        k_squash_fin<<<NB * 16, 256, 0, stream>>>(spart, out, NB, b0);
        }
    }
}

// Round 8
// 1036.190 us; speedup vs baseline: 2.0699x; 1.5109x over previous
//
#include <hip/hip_runtime.h>
#include <hip/hip_bf16.h>
#include <stdint.h>
#include <math.h>

#define NIN_  512
#define NOUT_ 128
#define CIN_  128
#define COUT_ 32
#define MO_   4096   // NOUT*COUT
#define NBT_  32     // build batch (all of B)
#define RB_   16     // routed b-half width
#define NPER_ 4      // n per route chunk
#define NQP_  128    // n-chunks (NIN_/NPER_)

typedef __attribute__((ext_vector_type(4))) float f32x4;

// ---------------------------------------------------------------------------
// K1 (fp32): u[n][bl(32)][mo] = sum_c W1[n][mo][c] * x[bl][n][c]
// grid = 512 n * 16 mo-tiles(256); block 256 = 4 waves.
// W staged in LDS as XOR-swizzled float4 units (conflict-free b128).
// (unchanged — proven R2/R4, near BW-bound)
// ---------------------------------------------------------------------------
__global__ __launch_bounds__(256) void k_build(const float* __restrict__ x,
                                               const float* __restrict__ W1,
                                               float* __restrict__ u) {
    const int n   = blockIdx.x >> 4;
    const int mt  = blockIdx.x & 15;
    const int mo0 = mt * 256;
    const int t   = threadIdx.x;
    const int l   = t & 63;
    const int bg  = t >> 6;

    __shared__ f32x4 xs4[32 * 32];   // [bl][cu]  16 KB
    __shared__ f32x4 ws4[256 * 8];   // swizzled   32 KB

    for (int k = t; k < NBT_ * 32; k += 256) {
        const int bl = k >> 5;
        const int cu = k & 31;
        xs4[k] = *(const f32x4*)(x + (((size_t)bl * NIN_ + n) * CIN_ + cu * 4));
    }

    const int cu8 = t & 7;
    const int row = t >> 3;

    float acc[4][8];
#pragma unroll
    for (int i = 0; i < 4; ++i)
#pragma unroll
        for (int j = 0; j < 8; ++j) acc[i][j] = 0.f;

    f32x4 wr[8];
#pragma unroll
    for (int p = 0; p < 8; ++p) {
        const int ml = row + p * 32;
        wr[p] = *(const f32x4*)(W1 + ((size_t)(n * MO_ + mo0 + ml) * CIN_ + 0 * 32 + cu8 * 4));
    }

    for (int ch = 0; ch < 4; ++ch) {
        __syncthreads();
#pragma unroll
        for (int p = 0; p < 8; ++p) {
            const int ml = row + p * 32;
            ws4[ml * 8 + (cu8 ^ (ml & 7))] = wr[p];
        }
        __syncthreads();
        if (ch < 3) {
#pragma unroll
            for (int p = 0; p < 8; ++p) {
                const int ml = row + p * 32;
                wr[p] = *(const f32x4*)(W1 + ((size_t)(n * MO_ + mo0 + ml) * CIN_ + (ch + 1) * 32 + cu8 * 4));
            }
        }
#pragma unroll
        for (int c4 = 0; c4 < 8; ++c4) {
            f32x4 wv[4];
#pragma unroll
            for (int i = 0; i < 4; ++i)
                wv[i] = ws4[(l + i * 64) * 8 + (c4 ^ (l & 7))];
            f32x4 xq[8];
#pragma unroll
            for (int j = 0; j < 8; ++j)
                xq[j] = xs4[(bg * 8 + j) * 32 + ch * 8 + c4];
#pragma unroll
            for (int i = 0; i < 4; ++i)
#pragma unroll
                for (int j = 0; j < 8; ++j) {
                    acc[i][j] += wv[i][0] * xq[j][0];
                    acc[i][j] += wv[i][1] * xq[j][1];
                    acc[i][j] += wv[i][2] * xq[j][2];
                    acc[i][j] += wv[i][3] * xq[j][3];
                }
        }
    }

#pragma unroll
    for (int i = 0; i < 4; ++i)
#pragma unroll
        for (int j = 0; j < 8; ++j)
            u[((size_t)n * NBT_ + bg * 8 + j) * MO_ + mo0 + i * 64 + l] = acc[i][j];
}

// ---------------------------------------------------------------------------
// K2 fused routing iteration (fp32) — R4 body verbatim, b-half addressing.
// MODE: 0 = uniform c, 1 = first agree (blog=0), 2 = normal
// grid = (RB_/4)*NQP_ = 512; block 256 = 4 waves; wave -> bl = bg*4+w (local
// 0..15); block -> chunk q of NPER_ n's. Global b = bofs + bl.
// Unit layout (R2/R4): f32x4 unit f = j*64+l; m = j*8 + (l>>3); o-quad = l&7.
// Wave-private softmax (shfl only, no LDS/barriers) — post-timing-safe.
// ---------------------------------------------------------------------------
template<int MODE>
__global__ __launch_bounds__(256) void k_route(const float* __restrict__ u,
                                               const float* __restrict__ vws,
                                               float* __restrict__ blog,
                                               float* __restrict__ spart,
                                               int bofs) {
    const int bg  = blockIdx.x & 3;
    const int q   = blockIdx.x >> 2;     // 0..NQP_-1
    const int w   = threadIdx.x >> 6;
    const int l   = threadIdx.x & 63;
    const int bl  = bg * 4 + w;          // local b 0..15
    const int sub = l >> 3;

    f32x4 vr[16];
    if (MODE != 0) {
#pragma unroll
        for (int j = 0; j < 16; ++j)
            vr[j] = *(const f32x4*)(vws + (size_t)bl * MO_ + (j * 64 + l) * 4);
    }

    f32x4 sacc[16];
#pragma unroll
    for (int j = 0; j < 16; ++j) sacc[j] = (f32x4){0.f, 0.f, 0.f, 0.f};

    for (int nn = 0; nn < NPER_; ++nn) {
        const int n = q * NPER_ + nn;
        const f32x4* up = (const f32x4*)(u + ((size_t)n * NBT_ + bofs + bl) * MO_);
        f32x4 ur[16];
#pragma unroll
        for (int j = 0; j < 16; ++j) ur[j] = up[j * 64 + l];

        if (MODE == 0) {
            const float cu = 1.0f / 128.0f;
#pragma unroll
            for (int j = 0; j < 16; ++j) {
                sacc[j][0] += cu * ur[j][0]; sacc[j][1] += cu * ur[j][1];
                sacc[j][2] += cu * ur[j][2]; sacc[j][3] += cu * ur[j][3];
            }
        } else {
            float* bp = blog + ((size_t)bl * NIN_ + n) * NOUT_;
            float bn[16];
            float mx = -1e30f;
#pragma unroll
            for (int j = 0; j < 16; ++j) {
                float p = vr[j][0] * ur[j][0] + vr[j][1] * ur[j][1]
                        + vr[j][2] * ur[j][2] + vr[j][3] * ur[j][3];
                p += __shfl_xor(p, 1, 64);
                p += __shfl_xor(p, 2, 64);
                p += __shfl_xor(p, 4, 64);
                const float old = (MODE == 1) ? 0.f : bp[j * 8 + sub];
                bn[j] = old + p;
                mx = fmaxf(mx, bn[j]);
            }
            if ((l & 7) == 0) {
#pragma unroll
                for (int j = 0; j < 16; ++j) bp[j * 8 + sub] = bn[j];
            }
            mx = fmaxf(mx, __shfl_xor(mx, 8, 64));
            mx = fmaxf(mx, __shfl_xor(mx, 16, 64));
            mx = fmaxf(mx, __shfl_xor(mx, 32, 64));
            float se = 0.f;
#pragma unroll
            for (int j = 0; j < 16; ++j) {
                bn[j] = expf(bn[j] - mx);
                se += bn[j];
            }
            se += __shfl_xor(se, 8, 64);
            se += __shfl_xor(se, 16, 64);
            se += __shfl_xor(se, 32, 64);
            const float inv = 1.0f / se;
#pragma unroll
            for (int j = 0; j < 16; ++j) {
                const float c = bn[j] * inv;
                sacc[j][0] += c * ur[j][0]; sacc[j][1] += c * ur[j][1];
                sacc[j][2] += c * ur[j][2]; sacc[j][3] += c * ur[j][3];
            }
        }
    }

    f32x4* sp = (f32x4*)(spart + ((size_t)q * RB_ + bl) * MO_);
#pragma unroll
    for (int j = 0; j < 16; ++j) sp[j * 64 + l] = sacc[j];
}

// ---------------------------------------------------------------------------
// K3: s = sum_q spart (NQP_ partials); v = |s|*s/(0.5+s^2) -> vws
// grid = RB_*MO_/256 = 256 blocks.
// ---------------------------------------------------------------------------
__global__ __launch_bounds__(256) void k_squash_mid(const float* __restrict__ spart,
                                                    float* __restrict__ vws) {
    const int j = blockIdx.x * 256 + threadIdx.x;   // bl*MO_ + mo (half-local)
    const size_t stride = (size_t)RB_ * MO_;
    float s = 0.f;
#pragma unroll 8
    for (int q = 0; q < NQP_; ++q) s += spart[q * stride + j];
    const float s2 = s * s;
    vws[j] = (sqrtf(s2) / (0.5f + s2)) * s;
}

// ---------------------------------------------------------------------------
// K4: final squash -> poses (fp32, [b][m][o]) + activations [b][m]
// ---------------------------------------------------------------------------
__global__ __launch_bounds__(256) void k_squash_fin(const float* __restrict__ spart,
                                                    float* __restrict__ out,
                                                    int b0) {
    const int j = blockIdx.x * 256 + threadIdx.x;   // bl*MO_ + mo (half-local)
    const size_t stride = (size_t)RB_ * MO_;
    float s = 0.f;
#pragma unroll 8
    for (int q = 0; q < NQP_; ++q) s += spart[q * stride + j];
    const float s2 = s * s;
    const float v = (sqrtf(s2) / (0.5f + s2)) * s;
    out[(size_t)b0 * MO_ + j] = v;

    float v2 = v * v;
#pragma unroll
    for (int d = 16; d >= 1; d >>= 1) v2 += __shfl_xor(v2, d, 64);
    if ((j & 31) == 0) {
        const int bl = j >> 12;
        const int m  = (j >> 5) & 127;
        out[131072 + (size_t)(b0 + bl) * NOUT_ + m] = sqrtf(v2);
    }
}

// ---------------------------------------------------------------------------
extern "C" void kernel_launch(void* const* d_in, const int* in_sizes, int n_in,
                              void* d_out, int out_size, void* d_ws, size_t ws_size,
                              hipStream_t stream) {
    const float* x  = (const float*)d_in[0];
    const float* W1 = (const float*)d_in[1];
    float* out = (float*)d_out;

    char* ws = (char*)d_ws;
    const size_t bytes_u  = (size_t)NBT_ * NIN_ * MO_ * 4;        // 268 MB
    const size_t bytes_bl = (size_t)RB_ * NIN_ * NOUT_ * 4;       // 4.2 MB
    const size_t bytes_v  = (size_t)RB_ * MO_ * 4;                // 0.26 MB
    const size_t bytes_sp = (size_t)NQP_ * RB_ * MO_ * 4;         // 33.5 MB
    const size_t need = bytes_u + bytes_bl + bytes_v + bytes_sp;
    if (ws_size < need) return;   // ws observed ≈ 4.3 GB; ample

    float* u     = (float*)(ws);
    float* blog  = (float*)(ws + bytes_u);
    float* vws   = (float*)(ws + bytes_u + bytes_bl);
    float* spart = (float*)(ws + bytes_u + bytes_bl + bytes_v);

    // build all 32 b at once: W read exactly once
    k_build<<<8192, 256, 0, stream>>>(x, W1, u);

    const int rgrid = (RB_ / 4) * NQP_;   // 512
    const int sgrid = (RB_ * MO_) / 256;  // 256

    // route each 16-b half fully (10 iterations) while its 134 MB u-half
    // stays Infinity-Cache-resident
    for (int h = 0; h < 2; ++h) {
        const int bofs = h * RB_;

        // iteration 1: uniform c (softmax of zeros)
        k_route<0><<<rgrid, 256, 0, stream>>>(u, vws, blog, spart, bofs);
        k_squash_mid<<<sgrid, 256, 0, stream>>>(spart, vws);

        for (int it = 1; it <= 9; ++it) {
            if (it == 1) k_route<1><<<rgrid, 256, 0, stream>>>(u, vws, blog, spart, bofs);
            else         k_route<2><<<rgrid, 256, 0, stream>>>(u, vws, blog, spart, bofs);
            if (it < 9) k_squash_mid<<<sgrid, 256, 0, stream>>>(spart, vws);
            else        k_squash_fin<<<sgrid, 256, 0, stream>>>(spart, out, bofs);
        }
    }
}